// Round 4
// baseline (312.793 us; speedup 1.0000x reference)
//
#include <hip/hip_runtime.h>
#include <math.h>

#define B_    32
#define S_    4096
#define DIN_  256
#define D_    256
#define T_    256
#define NB_   4
#define K_    5
#define EPS_  1e-5f
#define ROWS_ (B_ * T_)   // 8192

#define MROWS 32          // logical rows per block: 16 output + 8 halo each side
#define GROWS 36          // +2 guard rows top/bottom (zero-padded conv, branch-free)
#define ASTR  264         // bf16 row stride (528 B = 16B-aligned)

typedef short  shortx8 __attribute__((ext_vector_type(8)));
typedef float  floatx4 __attribute__((ext_vector_type(4)));

__device__ __forceinline__ unsigned short f2bf(float f) {
    unsigned int u = __float_as_uint(f);
    u += 0x7FFFu + ((u >> 16) & 1u);
    return (unsigned short)(u >> 16);
}
__device__ __forceinline__ float bf2f(unsigned short h) {
    return __uint_as_float(((unsigned int)h) << 16);
}

// ---------------------------------------------------------------------------
// Setup kernel: weight transpose+convert (z=0..8) and batch lengths (z=9).
// z: 0=in_w, 1..4=win_w[i], 5..8=wout_w[i], 9=lengths (mask dtype-detected).
// ---------------------------------------------------------------------------
__global__ void k_setup(const float* __restrict__ in_w, const float* __restrict__ win_w,
                        const float* __restrict__ wout_w, const unsigned int* __restrict__ mask_w,
                        unsigned short* __restrict__ wt_in, unsigned short* __restrict__ wt_win,
                        unsigned short* __restrict__ wt_wout, int* __restrict__ lengths) {
    int z = blockIdx.z;
    int tid = threadIdx.x;

    if (z == 9) {
        int b = blockIdx.y * 16 + blockIdx.x;
        if (b >= B_) return;
        // mask dtype detection (validated R1-R3): int32 / uint8 / float32
        int mode = 0;
        unsigned int w0 = mask_w[0];
        if (w0 == 0x3F800000u) mode = 2;
        else {
            bool u8 = false;
            for (int i = 0; i < 32; ++i)
                if (mask_w[i * 1024] > 1u) { u8 = true; break; }
            mode = u8 ? 1 : 0;
        }
        int s = 0;
        if (mode == 0) {
            const int* m = (const int*)mask_w;
            for (int i = tid; i < S_; i += 256) s += (m[(size_t)b * S_ + i] != 0);
        } else if (mode == 2) {
            const float* m = (const float*)mask_w;
            for (int i = tid; i < S_; i += 256) s += (m[(size_t)b * S_ + i] != 0.0f);
        } else {
            const unsigned char* m = (const unsigned char*)mask_w;
            for (int i = tid; i < S_; i += 256) s += (m[(size_t)b * S_ + i] != 0);
        }
        __shared__ int sm[256];
        sm[tid] = s;
        __syncthreads();
        for (int off = 128; off > 0; off >>= 1) {
            if (tid < off) sm[tid] += sm[tid + off];
            __syncthreads();
        }
        if (tid == 0) lengths[b] = sm[0];
        return;
    }

    const float* src; unsigned short* dst; int N, Kd;
    if (z == 0)      { src = in_w;                                   dst = wt_in;                                   N = D_;     Kd = DIN_; }
    else if (z <= 4) { src = win_w  + (size_t)(z - 1) * D_ * 2 * D_; dst = wt_win  + (size_t)(z - 1) * 2 * D_ * D_; N = 2 * D_; Kd = D_; }
    else             { src = wout_w + (size_t)(z - 5) * D_ * D_;     dst = wt_wout + (size_t)(z - 5) * D_ * D_;     N = D_;     Kd = D_; }
    int bx = blockIdx.x * 32;
    int by = blockIdx.y * 32;
    if (bx >= N) return;
    __shared__ float tile[32][33];
    int tx = tid & 31, ty = tid >> 5;
#pragma unroll
    for (int i = 0; i < 32; i += 8)
        tile[ty + i][tx] = src[(size_t)(by + ty + i) * N + bx + tx];
    __syncthreads();
#pragma unroll
    for (int i = 0; i < 32; i += 8)
        dst[(size_t)(bx + ty + i) * Kd + by + tx] = f2bf(tile[tx][ty + i]);
}

// ---------------------------------------------------------------------------
// GEMM helper: hreg[nn][mt][4] (+)= A(LDS, logical rows) @ W[N][256]^T + bias.
// Wave w owns n-tiles {w, w+8}; 2 m-tiles; depth-8 weight prefetch.
// ---------------------------------------------------------------------------
template<bool INIT>
__device__ __forceinline__ void gemm2(
    const unsigned short (*A)[ASTR], const unsigned short* __restrict__ wt,
    const float* __restrict__ bias, float (&hreg)[2][2][4],
    int w, int c16, int q)
{
#pragma unroll
    for (int nn = 0; nn < 2; ++nn) {
        int nt = w + nn * 8;
        const unsigned short* wp = wt + (size_t)(nt * 16 + c16) * 256 + q * 8;
        shortx8 Bf[8];
#pragma unroll
        for (int kk = 0; kk < 8; ++kk) Bf[kk] = *(const shortx8*)(wp + kk * 32);
        floatx4 acc[2] = {};
#pragma unroll
        for (int kk = 0; kk < 8; ++kk) {
#pragma unroll
            for (int mt = 0; mt < 2; ++mt) {
                shortx8 a = *(const shortx8*)&A[2 + mt * 16 + c16][kk * 32 + q * 8];
                acc[mt] = __builtin_amdgcn_mfma_f32_16x16x32_bf16(a, Bf[kk], acc[mt], 0, 0, 0);
            }
        }
        float ob = bias[nt * 16 + c16];
#pragma unroll
        for (int mt = 0; mt < 2; ++mt)
#pragma unroll
            for (int r = 0; r < 4; ++r) {
                float v = acc[mt][r] + ob;
                if (INIT) hreg[nn][mt][r] = v; else hreg[nn][mt][r] += v;
            }
    }
}

// ---------------------------------------------------------------------------
// Row stats (mu, rsig) over register-resident h. 2 internal syncs.
// ---------------------------------------------------------------------------
__device__ __forceinline__ void stats_pass(
    const float (&hreg)[2][2][4], float2* st,
    float (*rowS)[MROWS], float (*rowSS)[MROWS],
    int tid, int w, int c16, int q)
{
#pragma unroll
    for (int mt = 0; mt < 2; ++mt)
#pragma unroll
        for (int r = 0; r < 4; ++r) {
            float v0 = hreg[0][mt][r], v1 = hreg[1][mt][r];
            float s = v0 + v1, ss = v0 * v0 + v1 * v1;
#pragma unroll
            for (int off = 1; off < 16; off <<= 1) {
                s += __shfl_xor(s, off);
                ss += __shfl_xor(ss, off);
            }
            if (c16 == 0) {
                rowS[w][mt * 16 + q * 4 + r] = s;
                rowSS[w][mt * 16 + q * 4 + r] = ss;
            }
        }
    __syncthreads();
    if (tid < MROWS) {
        float s = 0.f, ss = 0.f;
#pragma unroll
        for (int i = 0; i < 8; ++i) { s += rowS[i][tid]; ss += rowSS[i][tid]; }
        float mu = s * (1.0f / D_);
        float var = ss * (1.0f / D_) - mu * mu;
        st[tid] = make_float2(mu, rsqrtf(var + EPS_));
    }
    __syncthreads();
}

// ---------------------------------------------------------------------------
// Mega-kernel. Grid 512 = 32 batches x 16 segments (16 out rows each).
// 512 threads / 8 waves; 2 blocks per CU (LDS 39 KB, VGPR capped at 128).
// ---------------------------------------------------------------------------
__global__ __launch_bounds__(512, 4) void k_mega(
    const float* __restrict__ x, const int* __restrict__ lengths,
    const unsigned short* __restrict__ wt_in, const float* __restrict__ in_b,
    const float* __restrict__ ln_g, const float* __restrict__ ln_b,
    const float* __restrict__ dw_w, const float* __restrict__ dw_b,
    const unsigned short* __restrict__ wt_win, const float* __restrict__ win_b,
    const unsigned short* __restrict__ wt_wout, const float* __restrict__ wout_b,
    const float* __restrict__ fn_g, const float* __restrict__ fn_b,
    float* __restrict__ out0, float* __restrict__ out1)
{
    __shared__ unsigned short buf0[GROWS][ASTR];   // 19 KB
    __shared__ unsigned short buf1[GROWS][ASTR];   // 19 KB
    __shared__ float2 st[MROWS];
    __shared__ float rowS[8][MROWS];
    __shared__ float rowSS[8][MROWS];

    int tid = threadIdx.x;
    int w = tid >> 6, lane = tid & 63;
    int c16 = lane & 15, q = lane >> 4;
    int bid = blockIdx.x;
    int b = bid >> 4, seg = bid & 15;
    int t0 = seg * 16 - 8;
    if (t0 < 0) t0 = 0;
    if (t0 > T_ - MROWS) t0 = T_ - MROWS;
    int out_lo = seg * 16;

    float hreg[2][2][4];
    int L = lengths[b];

    // ---- compress -> buf0 logical rows (bf16) ----
    {
        int ccol = tid & 255, r0 = tid >> 8;
        float Lf = (float)L;
        float hi = fmaxf(Lf - 1.0f, 0.0f);
        int L1 = max(L - 1, 0);
        const float* xb = x + (size_t)b * S_ * DIN_ + ccol;
#pragma unroll
        for (int e = 0; e < 16; ++e) {
            int row = r0 + e * 2;
            int t = t0 + row;
            float src = ((float)t + 0.5f) * (Lf * (1.0f / T_)) - 0.5f;
            src = fminf(fmaxf(src, 0.0f), hi);
            int i0 = (int)floorf(src);
            int i1 = min(i0 + 1, L1);
            float wf = src - (float)i0;
            float v0 = xb[(size_t)i0 * DIN_];
            float v1 = xb[(size_t)i1 * DIN_];
            buf0[2 + row][ccol] = f2bf((1.0f - wf) * v0 + wf * v1);
        }
    }
    __syncthreads();

    // ---- in-proj ----
    gemm2<true>(buf0, wt_in, in_b, hreg, w, c16, q);

    // ---- 4 conv blocks ----
    for (int li = 0; li < NB_; ++li) {
        const float* g_i = ln_g + li * D_;
        const float* b_i = ln_b + li * D_;
        const float* dww = dw_w + li * D_ * K_;
        const float* dwb = dw_b + li * D_;
        const unsigned short* ww = wt_win + (size_t)li * 2 * D_ * D_;
        const float* wb = win_b + li * 2 * D_;
        const unsigned short* ow = wt_wout + (size_t)li * D_ * D_;
        const float* ob = wout_b + li * D_;

        stats_pass(hreg, st, rowS, rowSS, tid, w, c16, q);

        // LN(h) -> buf0; also zero the 4 guard rows (1024 entries, 2/thread)
#pragma unroll
        for (int nn = 0; nn < 2; ++nn) {
            int col = (w + nn * 8) * 16 + c16;
            float gg = g_i[col], bb = b_i[col];
#pragma unroll
            for (int mt = 0; mt < 2; ++mt)
#pragma unroll
                for (int r = 0; r < 4; ++r) {
                    int row = mt * 16 + q * 4 + r;
                    float2 s = st[row];
                    buf0[2 + row][col] = f2bf((hreg[nn][mt][r] - s.x) * s.y * gg + bb);
                }
        }
        {
            int idx = tid;
#pragma unroll
            for (int zz = 0; zz < 2; ++zz, idx += 512) {
                int gr = idx >> 8;                    // 0..3
                int p = (gr < 2) ? gr : gr + 32;      // 0,1,34,35
                buf0[p][idx & 255] = 0;
            }
        }
        __syncthreads();

        // depthwise conv buf0 -> buf1 (guards make taps branch-free)
        {
            int ccol = tid & 255, r0 = tid >> 8;
            float wk[K_];
#pragma unroll
            for (int k = 0; k < K_; ++k) wk[k] = dww[ccol * K_ + k];
            float cb = dwb[ccol];
#pragma unroll
            for (int e = 0; e < 16; ++e) {
                int row = r0 + e * 2;
                float acc = cb;
#pragma unroll
                for (int k = 0; k < K_; ++k)
                    acc += bf2f(buf0[row + k][ccol]) * wk[k];
                buf1[2 + row][ccol] = f2bf(acc);
            }
        }
        __syncthreads();

        // win GEMM: 4 n-tiles (w+nn*8 over N=512); gate=nn 0,1 / val=nn 2,3
        float gvreg[4][2][4];
#pragma unroll
        for (int nn = 0; nn < 4; ++nn) {
            int nt = w + nn * 8;
            const unsigned short* wp = ww + (size_t)(nt * 16 + c16) * 256 + q * 8;
            shortx8 Bf[8];
#pragma unroll
            for (int kk = 0; kk < 8; ++kk) Bf[kk] = *(const shortx8*)(wp + kk * 32);
            floatx4 acc[2] = {};
#pragma unroll
            for (int kk = 0; kk < 8; ++kk) {
#pragma unroll
                for (int mt = 0; mt < 2; ++mt) {
                    shortx8 a = *(const shortx8*)&buf1[2 + mt * 16 + c16][kk * 32 + q * 8];
                    acc[mt] = __builtin_amdgcn_mfma_f32_16x16x32_bf16(a, Bf[kk], acc[mt], 0, 0, 0);
                }
            }
            float bb = wb[nt * 16 + c16];
#pragma unroll
            for (int mt = 0; mt < 2; ++mt)
#pragma unroll
                for (int r = 0; r < 4; ++r) gvreg[nn][mt][r] = acc[mt][r] + bb;
        }

        // act -> buf0: sigmoid(gate) * gelu_tanh(val); gelu ~ v*sigmoid(2u)
#pragma unroll
        for (int pp = 0; pp < 2; ++pp) {
            int col = (w + pp * 8) * 16 + c16;
#pragma unroll
            for (int mt = 0; mt < 2; ++mt)
#pragma unroll
                for (int r = 0; r < 4; ++r) {
                    float gate = gvreg[pp][mt][r];
                    float val  = gvreg[pp + 2][mt][r];
                    float sg = 1.0f / (1.0f + __expf(-gate));
                    float u = 1.5957691216f * (val + 0.044715f * val * val * val); // 2*sqrt(2/pi)
                    float ge = val / (1.0f + __expf(-u));
                    buf0[2 + mt * 16 + q * 4 + r][col] = f2bf(sg * ge);
                }
        }
        __syncthreads();

        // wout GEMM: h += act @ wout + wout_b
        gemm2<false>(buf0, ow, ob, hreg, w, c16, q);
    }

    // ---- final LN -> out0 (only the 16 owned rows) ----
    stats_pass(hreg, st, rowS, rowSS, tid, w, c16, q);
#pragma unroll
    for (int nn = 0; nn < 2; ++nn) {
        int col = (w + nn * 8) * 16 + c16;
        float gg = fn_g[col], bb = fn_b[col];
#pragma unroll
        for (int mt = 0; mt < 2; ++mt)
#pragma unroll
            for (int r = 0; r < 4; ++r) {
                int row = mt * 16 + q * 4 + r;
                int t = t0 + row;
                int tl = t - out_lo;
                if (tl >= 0 && tl < 16) {
                    float2 s = st[row];
                    out0[((size_t)b * T_ + t) * D_ + col] =
                        (hreg[nn][mt][r] - s.x) * s.y * gg + bb;
                }
            }
    }
    if (tid < 16) out1[(size_t)b * T_ + out_lo + tid] = 1.0f;
}

// ---------------------------------------------------------------------------
extern "C" void kernel_launch(void* const* d_in, const int* in_sizes, int n_in,
                              void* d_out, int out_size, void* d_ws, size_t ws_size,
                              hipStream_t stream) {
    const float* x      = (const float*)d_in[0];
    const unsigned int* mask_w = (const unsigned int*)d_in[1];
    const float* in_w   = (const float*)d_in[2];
    const float* in_b   = (const float*)d_in[3];
    const float* ln_g   = (const float*)d_in[4];
    const float* ln_b   = (const float*)d_in[5];
    const float* dw_w   = (const float*)d_in[6];
    const float* dw_b   = (const float*)d_in[7];
    const float* win_w  = (const float*)d_in[8];
    const float* win_b  = (const float*)d_in[9];
    const float* wout_w = (const float*)d_in[10];
    const float* wout_b = (const float*)d_in[11];
    const float* fn_g   = (const float*)d_in[12];
    const float* fn_b   = (const float*)d_in[13];

    char* w8 = (char*)d_ws;
    unsigned short* wt_in   = (unsigned short*)w8;                 // 128 KB
    unsigned short* wt_win  = wt_in  + (size_t)D_ * DIN_;          // 1 MB
    unsigned short* wt_wout = wt_win + (size_t)NB_ * 2 * D_ * D_;  // 512 KB
    int* lengths = (int*)(w8 + (4u << 20));

    float* out0 = (float*)d_out;
    float* out1 = out0 + (size_t)ROWS_ * D_;

    k_setup<<<dim3(16, 8, 10), 256, 0, stream>>>(in_w, win_w, wout_w, mask_w,
                                                 wt_in, wt_win, wt_wout, lengths);
    k_mega<<<512, 512, 0, stream>>>(x, lengths, wt_in, in_b, ln_g, ln_b, dw_w, dw_b,
                                    wt_win, win_b, wt_wout, wout_b, fn_g, fn_b,
                                    out0, out1);
}

// Round 5
// 293.312 us; speedup vs baseline: 1.0664x; 1.0664x over previous
//
#include <hip/hip_runtime.h>
#include <math.h>

#define B_    32
#define S_    4096
#define DIN_  256
#define D_    256
#define T_    256
#define NB_   4
#define K_    5
#define EPS_  1e-5f
#define ROWS_ (B_ * T_)   // 8192

#define ORS_  32          // owned rows per block (no GEMM redundancy)
#define HR_   36          // owned + 2 halo rows each side (conv radius 2)
#define ASTR  264         // bf16 row stride (528 B = 33*16B: 16B-aligned, odd/16)

typedef short  shortx8 __attribute__((ext_vector_type(8)));
typedef float  floatx4 __attribute__((ext_vector_type(4)));

__device__ __forceinline__ unsigned short f2bf(float f) {
    unsigned int u = __float_as_uint(f);
    u += 0x7FFFu + ((u >> 16) & 1u);
    return (unsigned short)(u >> 16);
}
__device__ __forceinline__ float bf2f_lo(unsigned int u) {
    return __uint_as_float(u << 16);
}
__device__ __forceinline__ float bf2f_hi(unsigned int u) {
    return __uint_as_float(u & 0xFFFF0000u);
}

// ---------------------------------------------------------------------------
// Setup: weight transpose+convert (z=0..8) and batch lengths (z=9).
// ---------------------------------------------------------------------------
__global__ void k_setup(const float* __restrict__ in_w, const float* __restrict__ win_w,
                        const float* __restrict__ wout_w, const unsigned int* __restrict__ mask_w,
                        unsigned short* __restrict__ wt_in, unsigned short* __restrict__ wt_win,
                        unsigned short* __restrict__ wt_wout, int* __restrict__ lengths) {
    int z = blockIdx.z;
    int tid = threadIdx.x;

    if (z == 9) {
        int b = blockIdx.y * 16 + blockIdx.x;
        if (b >= B_) return;
        int mode = 0;   // mask dtype detection (validated R1-R4)
        unsigned int w0 = mask_w[0];
        if (w0 == 0x3F800000u) mode = 2;
        else {
            bool u8 = false;
            for (int i = 0; i < 32; ++i)
                if (mask_w[i * 1024] > 1u) { u8 = true; break; }
            mode = u8 ? 1 : 0;
        }
        int s = 0;
        if (mode == 0) {
            const int* m = (const int*)mask_w;
            for (int i = tid; i < S_; i += 256) s += (m[(size_t)b * S_ + i] != 0);
        } else if (mode == 2) {
            const float* m = (const float*)mask_w;
            for (int i = tid; i < S_; i += 256) s += (m[(size_t)b * S_ + i] != 0.0f);
        } else {
            const unsigned char* m = (const unsigned char*)mask_w;
            for (int i = tid; i < S_; i += 256) s += (m[(size_t)b * S_ + i] != 0);
        }
        __shared__ int sm[256];
        sm[tid] = s;
        __syncthreads();
        for (int off = 128; off > 0; off >>= 1) {
            if (tid < off) sm[tid] += sm[tid + off];
            __syncthreads();
        }
        if (tid == 0) lengths[b] = sm[0];
        return;
    }

    const float* src; unsigned short* dst; int N, Kd;
    if (z == 0)      { src = in_w;                                   dst = wt_in;                                   N = D_;     Kd = DIN_; }
    else if (z <= 4) { src = win_w  + (size_t)(z - 1) * D_ * 2 * D_; dst = wt_win  + (size_t)(z - 1) * 2 * D_ * D_; N = 2 * D_; Kd = D_; }
    else             { src = wout_w + (size_t)(z - 5) * D_ * D_;     dst = wt_wout + (size_t)(z - 5) * D_ * D_;     N = D_;     Kd = D_; }
    int bx = blockIdx.x * 32;
    int by = blockIdx.y * 32;
    if (bx >= N) return;
    __shared__ float tile[32][33];
    int tx = tid & 31, ty = tid >> 5;
#pragma unroll
    for (int i = 0; i < 32; i += 8)
        tile[ty + i][tx] = src[(size_t)(by + ty + i) * N + bx + tx];
    __syncthreads();
#pragma unroll
    for (int i = 0; i < 32; i += 8)
        dst[(size_t)(bx + ty + i) * Kd + by + tx] = f2bf(tile[tx][ty + i]);
}

// ---------------------------------------------------------------------------
// Front: compress + in-proj -> h0 (fp32 global). 256 blocks x 32 rows.
// ---------------------------------------------------------------------------
__global__ __launch_bounds__(512, 2) void k_front(
    const float* __restrict__ x, const int* __restrict__ lengths,
    const unsigned short* __restrict__ wt_in, const float* __restrict__ in_b,
    float* __restrict__ h0)
{
    __shared__ unsigned short bufC[ORS_][ASTR];
    int tid = threadIdx.x;
    int w = tid >> 6, lane = tid & 63;
    int c16 = lane & 15, q = lane >> 4;
    int b = blockIdx.x >> 3, seg = blockIdx.x & 7;
    int t0 = seg * ORS_;
    int L = lengths[b];
    {
        int col = tid & 255, r0 = tid >> 8;
        float Lf = (float)L;
        float hi = fmaxf(Lf - 1.0f, 0.0f);
        int L1 = max(L - 1, 0);
        const float* xb = x + (size_t)b * S_ * DIN_ + col;
#pragma unroll
        for (int e = 0; e < 16; ++e) {
            int row = r0 + e * 2;
            int t = t0 + row;
            float src = ((float)t + 0.5f) * (Lf * (1.0f / T_)) - 0.5f;
            src = fminf(fmaxf(src, 0.0f), hi);
            int i0 = (int)floorf(src);
            int i1 = min(i0 + 1, L1);
            float wf = src - (float)i0;
            float v0 = xb[(size_t)i0 * DIN_];
            float v1 = xb[(size_t)i1 * DIN_];
            bufC[row][col] = f2bf((1.0f - wf) * v0 + wf * v1);
        }
    }
    __syncthreads();
#pragma unroll
    for (int nn = 0; nn < 2; ++nn) {
        int nt = w + nn * 8;
        const unsigned short* wp = wt_in + (size_t)(nt * 16 + c16) * 256 + q * 8;
        shortx8 Bf[8];
#pragma unroll
        for (int kk = 0; kk < 8; ++kk) Bf[kk] = *(const shortx8*)(wp + kk * 32);
        floatx4 acc[2] = {};
#pragma unroll
        for (int kk = 0; kk < 8; ++kk)
#pragma unroll
            for (int mt = 0; mt < 2; ++mt) {
                shortx8 a = *(const shortx8*)&bufC[mt * 16 + c16][kk * 32 + q * 8];
                acc[mt] = __builtin_amdgcn_mfma_f32_16x16x32_bf16(a, Bf[kk], acc[mt], 0, 0, 0);
            }
        float ob = in_b[nt * 16 + c16];
#pragma unroll
        for (int mt = 0; mt < 2; ++mt)
#pragma unroll
            for (int r = 0; r < 4; ++r) {
                int row = mt * 16 + q * 4 + r;
                h0[((size_t)b * T_ + t0 + row) * D_ + nt * 16 + c16] = acc[mt][r] + ob;
            }
    }
}

// ---------------------------------------------------------------------------
// One conv block: LN (halo-exact) -> dwconv -> win+act -> wout+residual.
// last==1: apply final LN and write out0/out1 instead of hout.
// ---------------------------------------------------------------------------
__global__ __launch_bounds__(512, 2) void k_blk(
    const float* __restrict__ hin, float* __restrict__ hout,
    const float* __restrict__ g_i, const float* __restrict__ b_i,
    const float* __restrict__ dww, const float* __restrict__ dwb,
    const unsigned short* __restrict__ ww, const float* __restrict__ wb,
    const unsigned short* __restrict__ ow, const float* __restrict__ ob,
    const float* __restrict__ fn_g, const float* __restrict__ fn_b,
    float* __restrict__ out0, float* __restrict__ out1, int last)
{
    __shared__ unsigned short buf0[HR_][ASTR];   // 19.0 KB
    __shared__ unsigned short buf1[ORS_][ASTR];  // 16.9 KB
    __shared__ float2 st[ORS_];
    __shared__ float rowS[8][ORS_];
    __shared__ float rowSS[8][ORS_];

    int tid = threadIdx.x;
    int w = tid >> 6, lane = tid & 63;
    int c16 = lane & 15, q = lane >> 4;
    int b = blockIdx.x >> 3, seg = blockIdx.x & 7;
    int t0 = seg * ORS_;

    // ---- Stage A: load h rows (own+halo), per-row stats, LN -> buf0 ----
    {
        float gv4[4], bv4[4];
#pragma unroll
        for (int i = 0; i < 4; ++i) { gv4[i] = g_i[lane + 64 * i]; bv4[i] = b_i[lane + 64 * i]; }
        float vv[5][4];
#pragma unroll
        for (int it = 0; it < 5; ++it) {
            int r = w + it * 8;
            int t = t0 - 2 + r;
            bool ok = (r < HR_) && (t >= 0) && (t < T_);
            int tc = min(max(t, 0), T_ - 1);
            const float* hp = hin + ((size_t)b * T_ + tc) * D_ + lane;
#pragma unroll
            for (int i = 0; i < 4; ++i) {
                float v = hp[64 * i];
                vv[it][i] = ok ? v : 0.0f;
            }
        }
#pragma unroll
        for (int it = 0; it < 5; ++it) {
            int r = w + it * 8;
            if (r < HR_) {
                float s  = vv[it][0] + vv[it][1] + vv[it][2] + vv[it][3];
                float ss = vv[it][0] * vv[it][0] + vv[it][1] * vv[it][1]
                         + vv[it][2] * vv[it][2] + vv[it][3] * vv[it][3];
#pragma unroll
                for (int off = 1; off < 64; off <<= 1) {
                    s += __shfl_xor(s, off);
                    ss += __shfl_xor(ss, off);
                }
                float mu = s * (1.0f / D_);
                float rsig = rsqrtf(ss * (1.0f / D_) - mu * mu + EPS_);
                int t = t0 - 2 + r;
                bool okt = (t >= 0) && (t < T_);
#pragma unroll
                for (int i = 0; i < 4; ++i) {
                    float ln = (vv[it][i] - mu) * rsig * gv4[i] + bv4[i];
                    buf0[r][lane + 64 * i] = okt ? f2bf(ln) : (unsigned short)0;
                }
            }
        }
    }
    // prefetch first win weight tile while LN drains / barrier
    shortx8 Bf[8];
    {
        const unsigned short* wp = ww + (size_t)(w * 16 + c16) * 256 + q * 8;
#pragma unroll
        for (int kk = 0; kk < 8; ++kk) Bf[kk] = *(const shortx8*)(wp + kk * 32);
    }
    __syncthreads();

    // ---- Stage B: depthwise conv buf0 -> buf1 (packed bf16x2) ----
    {
        int cp = tid & 127;
        int rg = tid >> 7;
        int col = cp * 2;
        float wk0[K_], wk1[K_];
#pragma unroll
        for (int k = 0; k < K_; ++k) { wk0[k] = dww[col * K_ + k]; wk1[k] = dww[(col + 1) * K_ + k]; }
        float cb0 = dwb[col], cb1 = dwb[col + 1];
#pragma unroll
        for (int e = 0; e < 8; ++e) {
            int rr = rg + e * 4;
            float a0 = cb0, a1 = cb1;
#pragma unroll
            for (int k = 0; k < K_; ++k) {
                unsigned int u = *(const unsigned int*)&buf0[rr + k][col];
                a0 += bf2f_lo(u) * wk0[k];
                a1 += bf2f_hi(u) * wk1[k];
            }
            unsigned int o = ((unsigned int)f2bf(a0)) | (((unsigned int)f2bf(a1)) << 16);
            *(unsigned int*)&buf1[rr][col] = o;
        }
    }
    __syncthreads();

    // ---- Stage C: win GEMM (pipelined weight prefetch) + act -> buf0 ----
    float gvreg[4][2][4];
#pragma unroll
    for (int nn = 0; nn < 4; ++nn) {
        shortx8 Bn[8];
        if (nn < 3) {
            const unsigned short* wp = ww + (size_t)((w + (nn + 1) * 8) * 16 + c16) * 256 + q * 8;
#pragma unroll
            for (int kk = 0; kk < 8; ++kk) Bn[kk] = *(const shortx8*)(wp + kk * 32);
        } else {
            const unsigned short* wp = ow + (size_t)(w * 16 + c16) * 256 + q * 8;  // wout tile 0
#pragma unroll
            for (int kk = 0; kk < 8; ++kk) Bn[kk] = *(const shortx8*)(wp + kk * 32);
        }
        floatx4 acc[2] = {};
#pragma unroll
        for (int kk = 0; kk < 8; ++kk)
#pragma unroll
            for (int mt = 0; mt < 2; ++mt) {
                shortx8 a = *(const shortx8*)&buf1[mt * 16 + c16][kk * 32 + q * 8];
                acc[mt] = __builtin_amdgcn_mfma_f32_16x16x32_bf16(a, Bf[kk], acc[mt], 0, 0, 0);
            }
        float bb = wb[(w + nn * 8) * 16 + c16];
#pragma unroll
        for (int mt = 0; mt < 2; ++mt)
#pragma unroll
            for (int r = 0; r < 4; ++r) gvreg[nn][mt][r] = acc[mt][r] + bb;
#pragma unroll
        for (int kk = 0; kk < 8; ++kk) Bf[kk] = Bn[kk];
    }
    // act: sigmoid(gate) * gelu_tanh(val) -> buf0 rows 0..31
#pragma unroll
    for (int pp = 0; pp < 2; ++pp) {
        int colw = (w + pp * 8) * 16 + c16;
#pragma unroll
        for (int mt = 0; mt < 2; ++mt)
#pragma unroll
            for (int r = 0; r < 4; ++r) {
                float gate = gvreg[pp][mt][r];
                float val  = gvreg[pp + 2][mt][r];
                float sg = 1.0f / (1.0f + __expf(-gate));
                float u = 1.5957691216f * (val + 0.044715f * val * val * val);
                float ge = val / (1.0f + __expf(-u));
                buf0[mt * 16 + q * 4 + r][colw] = f2bf(sg * ge);
            }
    }
    __syncthreads();

    // ---- Stage D: wout GEMM + residual ----
    float vreg[2][2][4];
#pragma unroll
    for (int nn = 0; nn < 2; ++nn) {
        int nt = w + nn * 8;
        shortx8 Bn[8];
        if (nn == 0) {
            const unsigned short* wp = ow + (size_t)((w + 8) * 16 + c16) * 256 + q * 8;
#pragma unroll
            for (int kk = 0; kk < 8; ++kk) Bn[kk] = *(const shortx8*)(wp + kk * 32);
        }
        float res[2][4];
#pragma unroll
        for (int mt = 0; mt < 2; ++mt)
#pragma unroll
            for (int r = 0; r < 4; ++r) {
                int row = mt * 16 + q * 4 + r;
                res[mt][r] = hin[((size_t)b * T_ + t0 + row) * D_ + nt * 16 + c16];
            }
        floatx4 acc[2] = {};
#pragma unroll
        for (int kk = 0; kk < 8; ++kk)
#pragma unroll
            for (int mt = 0; mt < 2; ++mt) {
                shortx8 a = *(const shortx8*)&buf0[mt * 16 + c16][kk * 32 + q * 8];
                acc[mt] = __builtin_amdgcn_mfma_f32_16x16x32_bf16(a, Bf[kk], acc[mt], 0, 0, 0);
            }
        float bb = ob[nt * 16 + c16];
#pragma unroll
        for (int mt = 0; mt < 2; ++mt)
#pragma unroll
            for (int r = 0; r < 4; ++r)
                vreg[nn][mt][r] = res[mt][r] + acc[mt][r] + bb;
        if (nn == 0) {
#pragma unroll
            for (int kk = 0; kk < 8; ++kk) Bf[kk] = Bn[kk];
        }
    }

    if (!last) {
#pragma unroll
        for (int nn = 0; nn < 2; ++nn)
#pragma unroll
            for (int mt = 0; mt < 2; ++mt)
#pragma unroll
                for (int r = 0; r < 4; ++r) {
                    int row = mt * 16 + q * 4 + r;
                    hout[((size_t)b * T_ + t0 + row) * D_ + (w + nn * 8) * 16 + c16] = vreg[nn][mt][r];
                }
    } else {
        // final LN over register-resident h' (cross-wave stats)
#pragma unroll
        for (int mt = 0; mt < 2; ++mt)
#pragma unroll
            for (int r = 0; r < 4; ++r) {
                float s = vreg[0][mt][r] + vreg[1][mt][r];
                float ss = vreg[0][mt][r] * vreg[0][mt][r] + vreg[1][mt][r] * vreg[1][mt][r];
#pragma unroll
                for (int off = 1; off < 16; off <<= 1) {
                    s += __shfl_xor(s, off);
                    ss += __shfl_xor(ss, off);
                }
                if (c16 == 0) {
                    rowS[w][mt * 16 + q * 4 + r] = s;
                    rowSS[w][mt * 16 + q * 4 + r] = ss;
                }
            }
        __syncthreads();
        if (tid < ORS_) {
            float s = 0.f, ss = 0.f;
#pragma unroll
            for (int i = 0; i < 8; ++i) { s += rowS[i][tid]; ss += rowSS[i][tid]; }
            float mu = s * (1.0f / D_);
            float var = ss * (1.0f / D_) - mu * mu;
            st[tid] = make_float2(mu, rsqrtf(var + EPS_));
        }
        __syncthreads();
#pragma unroll
        for (int nn = 0; nn < 2; ++nn) {
            int col = (w + nn * 8) * 16 + c16;
            float gg = fn_g[col], bb = fn_b[col];
#pragma unroll
            for (int mt = 0; mt < 2; ++mt)
#pragma unroll
                for (int r = 0; r < 4; ++r) {
                    int row = mt * 16 + q * 4 + r;
                    float2 sv = st[row];
                    out0[((size_t)b * T_ + t0 + row) * D_ + col] =
                        (vreg[nn][mt][r] - sv.x) * sv.y * gg + bb;
                }
        }
        if (tid < ORS_) out1[(size_t)b * T_ + t0 + tid] = 1.0f;
    }
}

// ---------------------------------------------------------------------------
extern "C" void kernel_launch(void* const* d_in, const int* in_sizes, int n_in,
                              void* d_out, int out_size, void* d_ws, size_t ws_size,
                              hipStream_t stream) {
    const float* x      = (const float*)d_in[0];
    const unsigned int* mask_w = (const unsigned int*)d_in[1];
    const float* in_w   = (const float*)d_in[2];
    const float* in_b   = (const float*)d_in[3];
    const float* ln_g   = (const float*)d_in[4];
    const float* ln_b   = (const float*)d_in[5];
    const float* dw_w   = (const float*)d_in[6];
    const float* dw_b   = (const float*)d_in[7];
    const float* win_w  = (const float*)d_in[8];
    const float* win_b  = (const float*)d_in[9];
    const float* wout_w = (const float*)d_in[10];
    const float* wout_b = (const float*)d_in[11];
    const float* fn_g   = (const float*)d_in[12];
    const float* fn_b   = (const float*)d_in[13];

    char* w8 = (char*)d_ws;
    unsigned short* wt_in   = (unsigned short*)w8;                 // 128 KB
    unsigned short* wt_win  = wt_in  + (size_t)D_ * DIN_;          // 1 MB
    unsigned short* wt_wout = wt_win + (size_t)NB_ * 2 * D_ * D_;  // 512 KB
    int* lengths = (int*)(w8 + (2u << 20));
    float* h0 = (float*)(w8 + (4u << 20));    // 8 MB
    float* h1 = (float*)(w8 + (12u << 20));   // 8 MB

    float* out0 = (float*)d_out;
    float* out1 = out0 + (size_t)ROWS_ * D_;

    k_setup<<<dim3(16, 8, 10), 256, 0, stream>>>(in_w, win_w, wout_w, mask_w,
                                                 wt_in, wt_win, wt_wout, lengths);
    k_front<<<256, 512, 0, stream>>>(x, lengths, wt_in, in_b, h0);

    for (int li = 0; li < NB_; ++li) {
        const float* hin = (li & 1) ? h1 : h0;
        float* hout      = (li & 1) ? h0 : h1;
        k_blk<<<256, 512, 0, stream>>>(
            hin, hout,
            ln_g + li * D_, ln_b + li * D_,
            dw_w + li * D_ * K_, dw_b + li * D_,
            wt_win + (size_t)li * 2 * D_ * D_, win_b + li * 2 * D_,
            wt_wout + (size_t)li * D_ * D_, wout_b + li * D_,
            fn_g, fn_b, out0, out1, li == 3 ? 1 : 0);
    }
}

// Round 6
// 285.155 us; speedup vs baseline: 1.0969x; 1.0286x over previous
//
#include <hip/hip_runtime.h>
#include <math.h>

#define B_    32
#define S_    4096
#define DIN_  256
#define D_    256
#define T_    256
#define NB_   4
#define K_    5
#define EPS_  1e-5f
#define ROWS_ (B_ * T_)   // 8192

#define ORS_  32          // owned rows per block
#define HR_   36          // owned + 2 halo rows each side
#define ASTR  264         // bf16 row stride (528 B, 16B-aligned)

typedef short  shortx8 __attribute__((ext_vector_type(8)));
typedef float  floatx4 __attribute__((ext_vector_type(4)));

__device__ __forceinline__ unsigned short f2bf(float f) {
    unsigned int u = __float_as_uint(f);
    u += 0x7FFFu + ((u >> 16) & 1u);
    return (unsigned short)(u >> 16);
}
__device__ __forceinline__ unsigned int pack2bf(float a, float b) {
    return (unsigned int)f2bf(a) | ((unsigned int)f2bf(b) << 16);
}
__device__ __forceinline__ float bf2f_lo(unsigned int u) {
    return __uint_as_float(u << 16);
}
__device__ __forceinline__ float bf2f_hi(unsigned int u) {
    return __uint_as_float(u & 0xFFFF0000u);
}

// ---------------------------------------------------------------------------
// Setup: weight transpose+convert (z=0..8) and batch lengths (z=9).
// ---------------------------------------------------------------------------
__global__ void k_setup(const float* __restrict__ in_w, const float* __restrict__ win_w,
                        const float* __restrict__ wout_w, const unsigned int* __restrict__ mask_w,
                        unsigned short* __restrict__ wt_in, unsigned short* __restrict__ wt_win,
                        unsigned short* __restrict__ wt_wout, int* __restrict__ lengths) {
    int z = blockIdx.z;
    int tid = threadIdx.x;

    if (z == 9) {
        int b = blockIdx.y * 16 + blockIdx.x;
        if (b >= B_) return;
        int mode = 0;   // mask dtype detection (validated R1-R5)
        unsigned int w0 = mask_w[0];
        if (w0 == 0x3F800000u) mode = 2;
        else {
            bool u8 = false;
            for (int i = 0; i < 32; ++i)
                if (mask_w[i * 1024] > 1u) { u8 = true; break; }
            mode = u8 ? 1 : 0;
        }
        int s = 0;
        if (mode == 0) {
            const int* m = (const int*)mask_w;
            for (int i = tid; i < S_; i += 256) s += (m[(size_t)b * S_ + i] != 0);
        } else if (mode == 2) {
            const float* m = (const float*)mask_w;
            for (int i = tid; i < S_; i += 256) s += (m[(size_t)b * S_ + i] != 0.0f);
        } else {
            const unsigned char* m = (const unsigned char*)mask_w;
            for (int i = tid; i < S_; i += 256) s += (m[(size_t)b * S_ + i] != 0);
        }
        __shared__ int sm[256];
        sm[tid] = s;
        __syncthreads();
        for (int off = 128; off > 0; off >>= 1) {
            if (tid < off) sm[tid] += sm[tid + off];
            __syncthreads();
        }
        if (tid == 0) lengths[b] = sm[0];
        return;
    }

    const float* src; unsigned short* dst; int N, Kd;
    if (z == 0)      { src = in_w;                                   dst = wt_in;                                   N = D_;     Kd = DIN_; }
    else if (z <= 4) { src = win_w  + (size_t)(z - 1) * D_ * 2 * D_; dst = wt_win  + (size_t)(z - 1) * 2 * D_ * D_; N = 2 * D_; Kd = D_; }
    else             { src = wout_w + (size_t)(z - 5) * D_ * D_;     dst = wt_wout + (size_t)(z - 5) * D_ * D_;     N = D_;     Kd = D_; }
    int bx = blockIdx.x * 32;
    int by = blockIdx.y * 32;
    if (bx >= N) return;
    __shared__ float tile[32][33];
    int tx = tid & 31, ty = tid >> 5;
#pragma unroll
    for (int i = 0; i < 32; i += 8)
        tile[ty + i][tx] = src[(size_t)(by + ty + i) * N + bx + tx];
    __syncthreads();
#pragma unroll
    for (int i = 0; i < 32; i += 8)
        dst[(size_t)(bx + ty + i) * Kd + by + tx] = f2bf(tile[tx][ty + i]);
}

// ---------------------------------------------------------------------------
// Front: compress + in-proj -> h0 (fp32 global). 256 blocks x 32 rows.
// ---------------------------------------------------------------------------
__global__ __launch_bounds__(512, 4) void k_front(
    const float* __restrict__ x, const int* __restrict__ lengths,
    const unsigned short* __restrict__ wt_in, const float* __restrict__ in_b,
    float* __restrict__ h0)
{
    __shared__ unsigned short bufC[ORS_][ASTR];
    int tid = threadIdx.x;
    int w = tid >> 6, lane = tid & 63;
    int c16 = lane & 15, q = lane >> 4;
    int b = blockIdx.x >> 3, seg = blockIdx.x & 7;
    int t0 = seg * ORS_;
    int L = lengths[b];
    {
        int tq = tid & 63, rg = tid >> 6;       // col quad, row group
        int col = tq * 4;
        float Lf = (float)L;
        float hi = fmaxf(Lf - 1.0f, 0.0f);
        int L1 = max(L - 1, 0);
        const float* xb = x + (size_t)b * S_ * DIN_ + col;
#pragma unroll
        for (int e = 0; e < 4; ++e) {
            int row = rg + e * 8;
            int t = t0 + row;
            float src = ((float)t + 0.5f) * (Lf * (1.0f / T_)) - 0.5f;
            src = fminf(fmaxf(src, 0.0f), hi);
            int i0 = (int)floorf(src);
            int i1 = min(i0 + 1, L1);
            float wf = src - (float)i0;
            float4 v0 = *(const float4*)&xb[(size_t)i0 * DIN_];
            float4 v1 = *(const float4*)&xb[(size_t)i1 * DIN_];
            uint2 o;
            o.x = pack2bf((1.0f - wf) * v0.x + wf * v1.x, (1.0f - wf) * v0.y + wf * v1.y);
            o.y = pack2bf((1.0f - wf) * v0.z + wf * v1.z, (1.0f - wf) * v0.w + wf * v1.w);
            *(uint2*)&bufC[row][col] = o;
        }
    }
    __syncthreads();
#pragma unroll
    for (int nn = 0; nn < 2; ++nn) {
        int nt = w + nn * 8;
        const unsigned short* wp = wt_in + (size_t)(nt * 16 + c16) * 256 + q * 8;
        shortx8 Bf[8];
#pragma unroll
        for (int kk = 0; kk < 8; ++kk) Bf[kk] = *(const shortx8*)(wp + kk * 32);
        floatx4 acc[2] = {};
#pragma unroll
        for (int kk = 0; kk < 8; ++kk)
#pragma unroll
            for (int mt = 0; mt < 2; ++mt) {
                shortx8 a = *(const shortx8*)&bufC[mt * 16 + c16][kk * 32 + q * 8];
                acc[mt] = __builtin_amdgcn_mfma_f32_16x16x32_bf16(a, Bf[kk], acc[mt], 0, 0, 0);
            }
        float ob = in_b[nt * 16 + c16];
#pragma unroll
        for (int mt = 0; mt < 2; ++mt)
#pragma unroll
            for (int r = 0; r < 4; ++r) {
                int row = mt * 16 + q * 4 + r;
                h0[((size_t)b * T_ + t0 + row) * D_ + nt * 16 + c16] = acc[mt][r] + ob;
            }
    }
}

// ---------------------------------------------------------------------------
// One conv block: LN (halo-exact) -> dwconv -> win+act -> wout+residual.
// last==1: apply final LN and write out0/out1 instead of hout.
// ---------------------------------------------------------------------------
__global__ __launch_bounds__(512, 4) void k_blk(
    const float* __restrict__ hin, float* __restrict__ hout,
    const float* __restrict__ g_i, const float* __restrict__ b_i,
    const float* __restrict__ dww, const float* __restrict__ dwb,
    const unsigned short* __restrict__ ww, const float* __restrict__ wb,
    const unsigned short* __restrict__ ow, const float* __restrict__ ob,
    const float* __restrict__ fn_g, const float* __restrict__ fn_b,
    float* __restrict__ out0, float* __restrict__ out1, int last)
{
    __shared__ unsigned short buf0[HR_][ASTR];   // 19.0 KB
    __shared__ unsigned short buf1[ORS_][ASTR];  // 16.9 KB
    __shared__ float2 st[ORS_];
    __shared__ float rowS[8][ORS_];
    __shared__ float rowSS[8][ORS_];

    int tid = threadIdx.x;
    int w = tid >> 6, lane = tid & 63;
    int c16 = lane & 15, q = lane >> 4;
    int b = blockIdx.x >> 3, seg = blockIdx.x & 7;
    int t0 = seg * ORS_;

    // ---- Stage A: load h (own+halo) as float4, row stats, LN -> buf0 packed ----
    {
        int c4 = lane * 4;
        float4 g4 = *(const float4*)&g_i[c4];
        float4 b4 = *(const float4*)&b_i[c4];
        float4 vv[5];
#pragma unroll
        for (int it = 0; it < 5; ++it) {
            int r = w + it * 8;
            int t = t0 - 2 + r;
            bool ok = (r < HR_) && (t >= 0) && (t < T_);
            int tc = min(max(t, 0), T_ - 1);
            float4 v = *(const float4*)&hin[((size_t)b * T_ + tc) * D_ + c4];
            vv[it].x = ok ? v.x : 0.0f;
            vv[it].y = ok ? v.y : 0.0f;
            vv[it].z = ok ? v.z : 0.0f;
            vv[it].w = ok ? v.w : 0.0f;
        }
#pragma unroll
        for (int it = 0; it < 5; ++it) {
            int r = w + it * 8;
            if (r < HR_) {
                float s  = vv[it].x + vv[it].y + vv[it].z + vv[it].w;
                float ss = vv[it].x * vv[it].x + vv[it].y * vv[it].y
                         + vv[it].z * vv[it].z + vv[it].w * vv[it].w;
#pragma unroll
                for (int off = 1; off < 64; off <<= 1) {
                    s += __shfl_xor(s, off);
                    ss += __shfl_xor(ss, off);
                }
                float mu = s * (1.0f / D_);
                float rsig = rsqrtf(ss * (1.0f / D_) - mu * mu + EPS_);
                uint2 o;
                o.x = pack2bf((vv[it].x - mu) * rsig * g4.x + b4.x,
                              (vv[it].y - mu) * rsig * g4.y + b4.y);
                o.y = pack2bf((vv[it].z - mu) * rsig * g4.z + b4.z,
                              (vv[it].w - mu) * rsig * g4.w + b4.w);
                int t = t0 - 2 + r;
                if (t < 0 || t >= T_) { o.x = 0; o.y = 0; }
                *(uint2*)&buf0[r][c4] = o;
            }
        }
    }
    // prefetch first win weight tile across the barrier
    shortx8 Bf[8];
    {
        const unsigned short* wp = ww + (size_t)(w * 16 + c16) * 256 + q * 8;
#pragma unroll
        for (int kk = 0; kk < 8; ++kk) Bf[kk] = *(const shortx8*)(wp + kk * 32);
    }
    __syncthreads();

    // ---- Stage B: depthwise conv buf0 -> buf1 (4 cols x 4 rows per thread) ----
    {
        int tq = tid & 63, rg = tid >> 6;
        int col = tq * 4;
        float4 wk[K_];
#pragma unroll
        for (int k = 0; k < K_; ++k) {
            wk[k].x = dww[(col + 0) * K_ + k];
            wk[k].y = dww[(col + 1) * K_ + k];
            wk[k].z = dww[(col + 2) * K_ + k];
            wk[k].w = dww[(col + 3) * K_ + k];
        }
        float4 cb4 = *(const float4*)&dwb[col];
#pragma unroll
        for (int e = 0; e < 4; ++e) {
            int rr = rg + e * 8;
            float4 acc = cb4;
#pragma unroll
            for (int k = 0; k < K_; ++k) {
                uint2 u = *(const uint2*)&buf0[rr + k][col];
                acc.x += bf2f_lo(u.x) * wk[k].x;
                acc.y += bf2f_hi(u.x) * wk[k].y;
                acc.z += bf2f_lo(u.y) * wk[k].z;
                acc.w += bf2f_hi(u.y) * wk[k].w;
            }
            uint2 o;
            o.x = pack2bf(acc.x, acc.y);
            o.y = pack2bf(acc.z, acc.w);
            *(uint2*)&buf1[rr][col] = o;
        }
    }
    __syncthreads();

    // ---- Stage C: win GEMM (pipelined weight prefetch) + act -> buf0 ----
    float gvreg[4][2][4];
#pragma unroll
    for (int nn = 0; nn < 4; ++nn) {
        shortx8 Bn[8];
        if (nn < 3) {
            const unsigned short* wp = ww + (size_t)((w + (nn + 1) * 8) * 16 + c16) * 256 + q * 8;
#pragma unroll
            for (int kk = 0; kk < 8; ++kk) Bn[kk] = *(const shortx8*)(wp + kk * 32);
        } else {
            const unsigned short* wp = ow + (size_t)(w * 16 + c16) * 256 + q * 8;  // wout tile 0
#pragma unroll
            for (int kk = 0; kk < 8; ++kk) Bn[kk] = *(const shortx8*)(wp + kk * 32);
        }
        floatx4 acc[2] = {};
#pragma unroll
        for (int kk = 0; kk < 8; ++kk)
#pragma unroll
            for (int mt = 0; mt < 2; ++mt) {
                shortx8 a = *(const shortx8*)&buf1[mt * 16 + c16][kk * 32 + q * 8];
                acc[mt] = __builtin_amdgcn_mfma_f32_16x16x32_bf16(a, Bf[kk], acc[mt], 0, 0, 0);
            }
        float bb = wb[(w + nn * 8) * 16 + c16];
#pragma unroll
        for (int mt = 0; mt < 2; ++mt)
#pragma unroll
            for (int r = 0; r < 4; ++r) gvreg[nn][mt][r] = acc[mt][r] + bb;
#pragma unroll
        for (int kk = 0; kk < 8; ++kk) Bf[kk] = Bn[kk];
    }
    // act: sigmoid(gate) * gelu_tanh(val) -> buf0 rows 0..31
#pragma unroll
    for (int pp = 0; pp < 2; ++pp) {
        int colw = (w + pp * 8) * 16 + c16;
#pragma unroll
        for (int mt = 0; mt < 2; ++mt)
#pragma unroll
            for (int r = 0; r < 4; ++r) {
                float gate = gvreg[pp][mt][r];
                float val  = gvreg[pp + 2][mt][r];
                float sg = 1.0f / (1.0f + __expf(-gate));
                float u = 1.5957691216f * (val + 0.044715f * val * val * val);
                float ge = val / (1.0f + __expf(-u));
                buf0[mt * 16 + q * 4 + r][colw] = f2bf(sg * ge);
            }
    }
    __syncthreads();

    // ---- Stage D: wout GEMM + residual ----
    float vreg[2][2][4];
#pragma unroll
    for (int nn = 0; nn < 2; ++nn) {
        int nt = w + nn * 8;
        shortx8 Bn[8];
        if (nn == 0) {
            const unsigned short* wp = ow + (size_t)((w + 8) * 16 + c16) * 256 + q * 8;
#pragma unroll
            for (int kk = 0; kk < 8; ++kk) Bn[kk] = *(const shortx8*)(wp + kk * 32);
        }
        float res[2][4];
#pragma unroll
        for (int mt = 0; mt < 2; ++mt)
#pragma unroll
            for (int r = 0; r < 4; ++r) {
                int row = mt * 16 + q * 4 + r;
                res[mt][r] = hin[((size_t)b * T_ + t0 + row) * D_ + nt * 16 + c16];
            }
        floatx4 acc[2] = {};
#pragma unroll
        for (int kk = 0; kk < 8; ++kk)
#pragma unroll
            for (int mt = 0; mt < 2; ++mt) {
                shortx8 a = *(const shortx8*)&buf0[mt * 16 + c16][kk * 32 + q * 8];
                acc[mt] = __builtin_amdgcn_mfma_f32_16x16x32_bf16(a, Bf[kk], acc[mt], 0, 0, 0);
            }
        float bb = ob[nt * 16 + c16];
#pragma unroll
        for (int mt = 0; mt < 2; ++mt)
#pragma unroll
            for (int r = 0; r < 4; ++r)
                vreg[nn][mt][r] = res[mt][r] + acc[mt][r] + bb;
        if (nn == 0) {
#pragma unroll
            for (int kk = 0; kk < 8; ++kk) Bf[kk] = Bn[kk];
        }
    }

    if (!last) {
#pragma unroll
        for (int nn = 0; nn < 2; ++nn)
#pragma unroll
            for (int mt = 0; mt < 2; ++mt)
#pragma unroll
                for (int r = 0; r < 4; ++r) {
                    int row = mt * 16 + q * 4 + r;
                    hout[((size_t)b * T_ + t0 + row) * D_ + (w + nn * 8) * 16 + c16] = vreg[nn][mt][r];
                }
    } else {
        // final LN over register-resident h' (cross-wave stats)
#pragma unroll
        for (int mt = 0; mt < 2; ++mt)
#pragma unroll
            for (int r = 0; r < 4; ++r) {
                float s = vreg[0][mt][r] + vreg[1][mt][r];
                float ss = vreg[0][mt][r] * vreg[0][mt][r] + vreg[1][mt][r] * vreg[1][mt][r];
#pragma unroll
                for (int off = 1; off < 16; off <<= 1) {
                    s += __shfl_xor(s, off);
                    ss += __shfl_xor(ss, off);
                }
                if (c16 == 0) {
                    rowS[w][mt * 16 + q * 4 + r] = s;
                    rowSS[w][mt * 16 + q * 4 + r] = ss;
                }
            }
        __syncthreads();
        if (tid < ORS_) {
            float s = 0.f, ss = 0.f;
#pragma unroll
            for (int i = 0; i < 8; ++i) { s += rowS[i][tid]; ss += rowSS[i][tid]; }
            float mu = s * (1.0f / D_);
            float var = ss * (1.0f / D_) - mu * mu;
            st[tid] = make_float2(mu, rsqrtf(var + EPS_));
        }
        __syncthreads();
#pragma unroll
        for (int nn = 0; nn < 2; ++nn) {
            int col = (w + nn * 8) * 16 + c16;
            float gg = fn_g[col], bb = fn_b[col];
#pragma unroll
            for (int mt = 0; mt < 2; ++mt)
#pragma unroll
                for (int r = 0; r < 4; ++r) {
                    int row = mt * 16 + q * 4 + r;
                    float2 sv = st[row];
                    out0[((size_t)b * T_ + t0 + row) * D_ + col] =
                        (vreg[nn][mt][r] - sv.x) * sv.y * gg + bb;
                }
        }
        if (tid < ORS_) out1[(size_t)b * T_ + t0 + tid] = 1.0f;
    }
}

// ---------------------------------------------------------------------------
extern "C" void kernel_launch(void* const* d_in, const int* in_sizes, int n_in,
                              void* d_out, int out_size, void* d_ws, size_t ws_size,
                              hipStream_t stream) {
    const float* x      = (const float*)d_in[0];
    const unsigned int* mask_w = (const unsigned int*)d_in[1];
    const float* in_w   = (const float*)d_in[2];
    const float* in_b   = (const float*)d_in[3];
    const float* ln_g   = (const float*)d_in[4];
    const float* ln_b   = (const float*)d_in[5];
    const float* dw_w   = (const float*)d_in[6];
    const float* dw_b   = (const float*)d_in[7];
    const float* win_w  = (const float*)d_in[8];
    const float* win_b  = (const float*)d_in[9];
    const float* wout_w = (const float*)d_in[10];
    const float* wout_b = (const float*)d_in[11];
    const float* fn_g   = (const float*)d_in[12];
    const float* fn_b   = (const float*)d_in[13];

    char* w8 = (char*)d_ws;
    unsigned short* wt_in   = (unsigned short*)w8;                 // 128 KB
    unsigned short* wt_win  = wt_in  + (size_t)D_ * DIN_;          // 1 MB
    unsigned short* wt_wout = wt_win + (size_t)NB_ * 2 * D_ * D_;  // 512 KB
    int* lengths = (int*)(w8 + (2u << 20));
    float* h0 = (float*)(w8 + (4u << 20));    // 8 MB
    float* h1 = (float*)(w8 + (12u << 20));   // 8 MB

    float* out0 = (float*)d_out;
    float* out1 = out0 + (size_t)ROWS_ * D_;

    k_setup<<<dim3(16, 8, 10), 256, 0, stream>>>(in_w, win_w, wout_w, mask_w,
                                                 wt_in, wt_win, wt_wout, lengths);
    k_front<<<256, 512, 0, stream>>>(x, lengths, wt_in, in_b, h0);

    for (int li = 0; li < NB_; ++li) {
        const float* hin = (li & 1) ? h1 : h0;
        float* hout      = (li & 1) ? h0 : h1;
        k_blk<<<256, 512, 0, stream>>>(
            hin, hout,
            ln_g + li * D_, ln_b + li * D_,
            dw_w + li * D_ * K_, dw_b + li * D_,
            wt_win + (size_t)li * 2 * D_ * D_, win_b + li * 2 * D_,
            wt_wout + (size_t)li * D_ * D_, wout_b + li * D_,
            fn_g, fn_b, out0, out1, li == 3 ? 1 : 0);
    }
}